// Round 5
// baseline (234.892 us; speedup 1.0000x reference)
//
#include <hip/hip_runtime.h>
#include <stdint.h>

// ---------------------------------------------------------------------------
// TripletRankingLoss — bit-exact JAX replication (absmax 0.0 verified R1/R3/R4,
// jax_threefry_partitionable=True scheme).
//
// R5: argmax_kernel is LATENCY-bound, not issue-bound (gfx94x-formula VALUBusy
// ~88% is ~2x overstated on gfx950 SIMD-32 => real ~44%). Fix:
//   - 4 independent threefry chains per lane (ILP=4, stride 256), validity-
//     masked tails, per-chain (bv,bi) trackers merged at the end.
//   - perm[] gathers for iteration it+1 prefetched before computing it
//     (issue-early / consume-late; clamped index keeps OOB harmless).
//   - x0 key-injections fused into the next round's add (v_add3, key in SGPR).
// Tie-break is an order-independent (value, min-index) pair-compare, so chain
// and visit order cannot change results. Draw words bit-identical to R1-R4.
// ---------------------------------------------------------------------------

#define B_ROWS 8192
#define DIMS   512
#define NLAB   16   // labels are 0..13; padded to 16

__device__ __forceinline__ uint32_t rotl(uint32_t x, uint32_t r) {
  return __builtin_amdgcn_alignbit(x, x, 32u - r);  // rotr(x, 32-r) == rotl(x, r)
}

// ---- compile-time threefry block for key derivation (pure literals) -------
struct KeyPair { uint32_t a, b; };
constexpr KeyPair tf_c(uint32_t k0, uint32_t k1, uint32_t x0, uint32_t x1) {
  const uint32_t ks2 = k0 ^ k1 ^ 0x1BD11BDAu;
  x0 += k0; x1 += k1;
#define TFRC(r) { x0 += x1; x1 = (uint32_t)((x1 << (r)) | (x1 >> (32 - (r)))); x1 ^= x0; }
  TFRC(13) TFRC(15) TFRC(26) TFRC(6)
  x0 += k1;  x1 += ks2 + 1u;
  TFRC(17) TFRC(29) TFRC(16) TFRC(24)
  x0 += ks2; x1 += k0 + 2u;
  TFRC(13) TFRC(15) TFRC(26) TFRC(6)
  x0 += k0;  x1 += k1 + 3u;
  TFRC(17) TFRC(29) TFRC(16) TFRC(24)
  x0 += k1;  x1 += ks2 + 4u;
  TFRC(13) TFRC(15) TFRC(26) TFRC(6)
  x0 += ks2; x1 += k0 + 5u;
#undef TFRC
  return {x0, x1};
}
// jax.random.key(42) -> (0,42); partitionable split -> block at counts (0, i)
constexpr KeyPair KP = tf_c(0u, 42u, 0u, 0u);  // keys for g_pos
constexpr KeyPair KN = tf_c(0u, 42u, 0u, 1u);  // keys for g_neg

// ---- runtime draw, keys as literals; x1_init = m + K1 precomputed ----------
// x0-injections fused into the following round's first add (v_add3 candidate).
template <uint32_t K0, uint32_t K1>
__device__ __forceinline__ uint32_t tf_draw(uint32_t x1) {
  constexpr uint32_t KS2 = K0 ^ K1 ^ 0x1BD11BDAu;
  uint32_t x0 = K0 + x1;                 // round 1 (init folds into literal add)
  x1 = rotl(x1, 13); x1 ^= x0;
  x0 += x1; x1 = rotl(x1, 15); x1 ^= x0;
  x0 += x1; x1 = rotl(x1, 26); x1 ^= x0;
  x0 += x1; x1 = rotl(x1, 6);  x1 ^= x0;
  x1 += KS2 + 1u;  x0 = x0 + x1 + K1;    // inject(K1, KS2+1) fused into round 5
  x1 = rotl(x1, 17); x1 ^= x0;
  x0 += x1; x1 = rotl(x1, 29); x1 ^= x0;
  x0 += x1; x1 = rotl(x1, 16); x1 ^= x0;
  x0 += x1; x1 = rotl(x1, 24); x1 ^= x0;
  x1 += K0 + 2u;   x0 = x0 + x1 + KS2;   // inject(KS2, K0+2) fused into round 9
  x1 = rotl(x1, 13); x1 ^= x0;
  x0 += x1; x1 = rotl(x1, 15); x1 ^= x0;
  x0 += x1; x1 = rotl(x1, 26); x1 ^= x0;
  x0 += x1; x1 = rotl(x1, 6);  x1 ^= x0;
  x1 += K1 + 3u;   x0 = x0 + x1 + K0;    // inject(K0, K1+3) fused into round 13
  x1 = rotl(x1, 17); x1 ^= x0;
  x0 += x1; x1 = rotl(x1, 29); x1 ^= x0;
  x0 += x1; x1 = rotl(x1, 16); x1 ^= x0;
  x0 += x1; x1 = rotl(x1, 24); x1 ^= x0;
  x1 += KS2 + 4u;  x0 = x0 + x1 + K1;    // inject(K1, KS2+4) fused into round 17
  x1 = rotl(x1, 13); x1 ^= x0;
  x0 += x1; x1 = rotl(x1, 15); x1 ^= x0;
  x0 += x1; x1 = rotl(x1, 26); x1 ^= x0;
  x0 += x1; x1 = rotl(x1, 6);  x1 ^= x0;
  return (x0 + KS2) ^ (x1 + K0 + 5u);    // final inject folded into output
}

// ---------------- kernel 0: stable counting sort by label ------------------
__global__ __launch_bounds__(256) void sort_kernel(const int* __restrict__ labels,
                                                   int* __restrict__ perm,
                                                   int* __restrict__ gstart) {
  __shared__ int cnt[NLAB][256];
  __shared__ int gs[NLAB + 1];
  const int t = threadIdx.x;
  for (int l = 0; l < NLAB; ++l) cnt[l][t] = 0;
  __syncthreads();
  const int base = t * 32;
  for (int e = base; e < base + 32; ++e) cnt[labels[e]][t]++;
  __syncthreads();
  if (t < NLAB) {
    int run = 0;
    for (int k = 0; k < 256; ++k) { const int c = cnt[t][k]; cnt[t][k] = run; run += c; }
    gs[t + 1] = run;
  }
  __syncthreads();
  if (t == 0) {
    gs[0] = 0;
    for (int l = 1; l <= NLAB; ++l) gs[l] += gs[l - 1];
  }
  __syncthreads();
  for (int e = base; e < base + 32; ++e) {
    const int l = labels[e];
    perm[gs[l] + cnt[l][t]++] = e;
  }
  if (t <= NLAB) gstart[t] = gs[t];
}

// --------------------------- kernel 1: row norms ---------------------------
__global__ __launch_bounds__(256) void norms_kernel(const float* __restrict__ pred,
                                                    float* __restrict__ norms) {
  const int wave = threadIdx.x >> 6, lane = threadIdx.x & 63;
  const int r = blockIdx.x * 4 + wave;
  const float4* A = (const float4*)(pred + (size_t)r * DIMS);
  float s = 0.f;
#pragma unroll
  for (int t = 0; t < 2; ++t) {
    const float4 a = A[lane + 64 * t];
    s += a.x * a.x + a.y * a.y + a.z * a.z + a.w * a.w;
  }
  for (int o = 32; o > 0; o >>= 1) s += __shfl_down(s, o, 64);
  if (lane == 0) norms[r] = sqrtf(s);
}

// ------------- kernel 2: gumbel argmax, one wave per row, ILP=4 ------------
__global__ __launch_bounds__(256) void argmax_kernel(const int* __restrict__ labels,
                                                     const int* __restrict__ perm,
                                                     const int* __restrict__ gstart,
                                                     int* __restrict__ idxp,
                                                     int* __restrict__ idxn) {
  const int lane = threadIdx.x & 63;
  const int r = blockIdx.x * 4 + (threadIdx.x >> 6);
  const int li = __builtin_amdgcn_readfirstlane(labels[r]);
  const int g0 = __builtin_amdgcn_readfirstlane(gstart[li]);
  const int g1 = __builtin_amdgcn_readfirstlane(gstart[li + 1]);
  const int glen = g1 - g0;
  const uint32_t base = (uint32_t)r << 13;  // r * 8192

  unsigned long long pp, pn;

  // -------- positive phase: own group [g0,g1), key KP --------
  {
    const uint32_t sb = base + KP.b;
    const int niter = (glen + 255) >> 8;
    int bv[4] = {-1, -1, -1, -1}, bi[4] = {0, 0, 0, 0};
    int j[4], jn[4];
    int tb = g0 + lane;
#pragma unroll
    for (int c = 0; c < 4; ++c) jn[c] = perm[min(tb + 64 * c, 8191)];
    for (int it = 0; it < niter; ++it) {
#pragma unroll
      for (int c = 0; c < 4; ++c) j[c] = jn[c];
      const int tbn = tb + 256;
#pragma unroll
      for (int c = 0; c < 4; ++c) jn[c] = perm[min(tbn + 64 * c, 8191)];  // prefetch
#pragma unroll
      for (int c = 0; c < 4; ++c) {
        const uint32_t w = tf_draw<KP.a, KP.b>(sb + (uint32_t)j[c]);
        const int t = tb + 64 * c;
        const int v = (t < g1) ? (int)(w >> 9) : -1;  // 23-bit draw; gumbel-monotonic
        const bool better =
            (v > bv[c]) || ((v == bv[c]) && ((unsigned)j[c] < (unsigned)bi[c]));
        bv[c] = better ? v : bv[c];
        bi[c] = better ? j[c] : bi[c];
      }
      tb = tbn;
    }
    int BV = bv[0], BI = bi[0];
#pragma unroll
    for (int c = 1; c < 4; ++c) {
      const bool better =
          (bv[c] > BV) || ((bv[c] == BV) && ((unsigned)bi[c] < (unsigned)BI));
      BV = better ? bv[c] : BV;
      BI = better ? bi[c] : BI;
    }
    pp = (((unsigned long long)(BV + 1)) << 13) | (unsigned)(8191 - BI);
  }

  // -------- negative phase: complement, key KN --------
  {
    const uint32_t sb = base + KN.b;
    const int nneg = B_ROWS - glen;
    const int niter = (nneg + 255) >> 8;
    int bv[4] = {-1, -1, -1, -1}, bi[4] = {0, 0, 0, 0};
    int j[4], jn[4];
    int tb = lane;
#pragma unroll
    for (int c = 0; c < 4; ++c) {
      const int t = tb + 64 * c;
      const int tj = (t < g0) ? t : t + glen;  // skip own group
      jn[c] = perm[min(tj, 8191)];
    }
    for (int it = 0; it < niter; ++it) {
#pragma unroll
      for (int c = 0; c < 4; ++c) j[c] = jn[c];
      const int tbn = tb + 256;
#pragma unroll
      for (int c = 0; c < 4; ++c) {  // prefetch next iteration's gathers
        const int t = tbn + 64 * c;
        const int tj = (t < g0) ? t : t + glen;
        jn[c] = perm[min(tj, 8191)];
      }
#pragma unroll
      for (int c = 0; c < 4; ++c) {
        const uint32_t w = tf_draw<KN.a, KN.b>(sb + (uint32_t)j[c]);
        const int t = tb + 64 * c;
        const int v = (t < nneg) ? (int)(w >> 9) : -1;
        const bool better =
            (v > bv[c]) || ((v == bv[c]) && ((unsigned)j[c] < (unsigned)bi[c]));
        bv[c] = better ? v : bv[c];
        bi[c] = better ? j[c] : bi[c];
      }
      tb = tbn;
    }
    int BV = bv[0], BI = bi[0];
#pragma unroll
    for (int c = 1; c < 4; ++c) {
      const bool better =
          (bv[c] > BV) || ((bv[c] == BV) && ((unsigned)bi[c] < (unsigned)BI));
      BV = better ? bv[c] : BV;
      BI = better ? bi[c] : BI;
    }
    pn = (((unsigned long long)(BV + 1)) << 13) | (unsigned)(8191 - BI);
  }

  // ---- wave reduce: max value, tie -> min index (packed) ----
  for (int o = 32; o > 0; o >>= 1) {
    const unsigned long long t1 = __shfl_down(pp, o, 64); if (t1 > pp) pp = t1;
    const unsigned long long t2 = __shfl_down(pn, o, 64); if (t2 > pn) pn = t2;
  }
  if (lane == 0) {
    idxp[r] = 8191 - (int)(pp & 8191ull);
    idxn[r] = 8191 - (int)(pn & 8191ull);
  }
}

// --------------- kernel 3: per-row cosine margin, relu -> cosv -------------
__global__ __launch_bounds__(256) void cos_kernel(const float* __restrict__ pred,
                                                  const float* __restrict__ norms,
                                                  const int* __restrict__ idxp,
                                                  const int* __restrict__ idxn,
                                                  float* __restrict__ cosv) {
  const int wave = threadIdx.x >> 6, lane = threadIdx.x & 63;
  const int r = blockIdx.x * 4 + wave;
  const int ip = idxp[r], inn = idxn[r];
  const float4* A = (const float4*)(pred + (size_t)r * DIMS);
  const float4* P = (const float4*)(pred + (size_t)ip * DIMS);
  const float4* Nn = (const float4*)(pred + (size_t)inn * DIMS);
  float dp = 0.f, dn = 0.f;
#pragma unroll
  for (int t = 0; t < 2; ++t) {
    const float4 a = A[lane + 64 * t];
    const float4 p = P[lane + 64 * t];
    const float4 n = Nn[lane + 64 * t];
    dp += a.x * p.x + a.y * p.y + a.z * p.z + a.w * p.w;
    dn += a.x * n.x + a.y * n.y + a.z * n.z + a.w * n.w;
  }
  for (int o = 32; o > 0; o >>= 1) {
    dp += __shfl_down(dp, o, 64);
    dn += __shfl_down(dn, o, 64);
  }
  if (lane == 0) {
    const float na = fmaxf(norms[r], 1e-6f);
    const float np = fmaxf(norms[ip], 1e-6f);
    const float nn = fmaxf(norms[inn], 1e-6f);
    const float c = dp / (na * np) - dn / (na * nn) + 0.1f;
    cosv[r] = fmaxf(c, 0.f);
  }
}

// --------------------- kernel 4: mean (double accumulate) ------------------
__global__ __launch_bounds__(256) void reduce_kernel(const float* __restrict__ cosv,
                                                     float* __restrict__ out) {
  __shared__ double sh[4];
  double s = 0.0;
  for (int j = threadIdx.x; j < B_ROWS; j += 256) s += (double)cosv[j];
  for (int o = 32; o > 0; o >>= 1) s += __shfl_down(s, o, 64);
  const int wave = threadIdx.x >> 6, lane = threadIdx.x & 63;
  if (lane == 0) sh[wave] = s;
  __syncthreads();
  if (threadIdx.x == 0) {
    const double t = sh[0] + sh[1] + sh[2] + sh[3];
    out[0] = (float)(t / (double)B_ROWS);
  }
}

extern "C" void kernel_launch(void* const* d_in, const int* in_sizes, int n_in,
                              void* d_out, int out_size, void* d_ws, size_t ws_size,
                              hipStream_t stream) {
  const float* pred  = (const float*)d_in[0];
  const int* labels  = (const int*)d_in[1];
  float* out = (float*)d_out;

  char* ws = (char*)d_ws;
  float* norms  = (float*)(ws + 0);
  int*   idxp   = (int*)(ws + 32 * 1024);
  int*   idxn   = (int*)(ws + 64 * 1024);
  float* cosv   = (float*)(ws + 96 * 1024);
  int*   perm   = (int*)(ws + 128 * 1024);
  int*   gstart = (int*)(ws + 160 * 1024);

  sort_kernel<<<1, 256, 0, stream>>>(labels, perm, gstart);
  norms_kernel<<<B_ROWS / 4, 256, 0, stream>>>(pred, norms);
  argmax_kernel<<<B_ROWS / 4, 256, 0, stream>>>(labels, perm, gstart, idxp, idxn);
  cos_kernel<<<B_ROWS / 4, 256, 0, stream>>>(pred, norms, idxp, idxn, cosv);
  reduce_kernel<<<1, 256, 0, stream>>>(cosv, out);
}